// Round 10
// baseline (285.759 us; speedup 1.0000x reference)
//
#include <hip/hip_runtime.h>

#define B_   8
#define N_   1024
#define D_   512
#define H_   8
#define DH_  64
#define SCALE_ 0.044194173824159216f   // 1/sqrt(512)
#define LOG2E_ 1.4426950408889634f

typedef __attribute__((ext_vector_type(8))) short bf16x8;
typedef __attribute__((ext_vector_type(4))) float f32x4;
typedef __attribute__((ext_vector_type(8))) unsigned short us8;
typedef __attribute__((ext_vector_type(4))) unsigned int u32x4;

__device__ __forceinline__ unsigned short f2bf(float f) {
  unsigned u = __builtin_bit_cast(unsigned, f);
  u += 0x7fffu + ((u >> 16) & 1u);           // RNE
  return (unsigned short)(u >> 16);
}
__device__ __forceinline__ float bf2f(unsigned short h) {
  unsigned u = ((unsigned)h) << 16;
  return __builtin_bit_cast(float, u);
}
__device__ __forceinline__ void gl_lds16(const void* g, void* l) {
  __builtin_amdgcn_global_load_lds(
      (const __attribute__((address_space(1))) unsigned int*)g,
      (__attribute__((address_space(3))) unsigned int*)l, 16, 0, 0);
}
__device__ __forceinline__ unsigned cvt_pk_bf16(float lo, float hi) {
  unsigned r;
  asm("v_cvt_pk_bf16_f32 %0, %1, %2" : "=v"(r) : "v"(lo), "v"(hi));
  return r;
}
#define MFMA16(a, b, c) __builtin_amdgcn_mfma_f32_16x16x32_bf16((a), (b), (c), 0, 0, 0)
#define SCHED_PIN() __builtin_amdgcn_sched_barrier(0)

// ---------------------------------------------------------------------------
// prep: WT_swz[mat][n][kmap] = bf16(W[k][n]); kmap XOR-swizzled so that a
// LINEAR global_load_lds copy + XOR on the ds_read side is bank-conflict-free.
// ---------------------------------------------------------------------------
__global__ void prep_w(const float* __restrict__ Wq, const float* __restrict__ Wk,
                       const float* __restrict__ Wv, const float* __restrict__ Wo,
                       unsigned short* __restrict__ WT) {
  int idx = blockIdx.x * 256 + threadIdx.x;          // 4 * 512 * 512 total
  int mat = idx >> 18;
  int rem = idx & 0x3FFFF;
  int k = rem >> 9, n = rem & 511;
  const float* W = (mat == 0) ? Wq : (mat == 1) ? Wk : (mat == 2) ? Wv : Wo;
  float v = W[(size_t)k * 512 + n];
  int kmap = (k & ~63) | ((k & 63) ^ ((n & 7) << 3));
  WT[(size_t)mat * 262144 + (size_t)n * 512 + kmap] = f2bf(v);
}

// mbits[j] bit b = (mask[b][j] != 0)
__global__ void prep_mask(const float* __restrict__ mask, unsigned* __restrict__ mbits) {
  int j = blockIdx.x * 256 + threadIdx.x;            // 1024 total
  unsigned r = 0;
#pragma unroll
  for (int bb = 0; bb < 8; ++bb) r |= (mask[bb * N_ + j] != 0.f ? 1u : 0u) << bb;
  mbits[j] = r;
}

// ---------------------------------------------------------------------------
// GEMM core body (128x128 tile, BK=64, 4 waves 2x2, wave = 64x64 out)
// ---------------------------------------------------------------------------
#define GEMM_BODY(A, W, bias, EPILOGUE)                                          \
  __shared__ unsigned short Alds[2][128][72];                                    \
  __shared__ unsigned short Blds[2][128 * 64];                                   \
  const int t = threadIdx.x, w = t >> 6, l = t & 63;                             \
  const int wr = w >> 1, wc = w & 1;                                             \
  const int lm = l & 15, lg = l >> 4;                                            \
  const int bm = blockIdx.x >> 2, bn = blockIdx.x & 3;                           \
  f32x4 acc[4][4];                                                               \
  _Pragma("unroll") for (int mt = 0; mt < 4; ++mt)                               \
  _Pragma("unroll") for (int nt = 0; nt < 4; ++nt)                               \
      acc[mt][nt] = f32x4{0.f, 0.f, 0.f, 0.f};                                   \
  float4 areg[8];                                                                \
  auto loadA = [&](int kt) {                                                     \
    _Pragma("unroll") for (int p = 0; p < 8; ++p) {                              \
      int row = (t >> 4) + p * 16, col = (t & 15) * 4;                           \
      areg[p] = *(const float4*)&A[((size_t)(bm * 128 + row)) * 512 + kt * 64 + col]; \
    }                                                                            \
  };                                                                             \
  auto issueB = [&](int kt, int sb) {                                            \
    _Pragma("unroll") for (int p = 0; p < 4; ++p) {                              \
      int chunk = w * 4 + p;                                                     \
      int row = chunk * 8 + (l >> 3), gc = kt * 64 + (l & 7) * 8;                \
      gl_lds16(&W[((size_t)(bn * 128 + row)) * 512 + gc],                        \
               &Blds[sb][chunk * 512 + l * 8]);                                  \
    }                                                                            \
  };                                                                             \
  auto writeA = [&](int sb) {                                                    \
    _Pragma("unroll") for (int p = 0; p < 8; ++p) {                              \
      int row = (t >> 4) + p * 16, col = (t & 15) * 4;                           \
      float4 v = areg[p];                                                        \
      uint2 d;                                                                   \
      d.x = (unsigned)f2bf(v.x) | ((unsigned)f2bf(v.y) << 16);                   \
      d.y = (unsigned)f2bf(v.z) | ((unsigned)f2bf(v.w) << 16);                   \
      *(uint2*)&Alds[sb][row][col] = d;                                          \
    }                                                                            \
  };                                                                             \
  loadA(0); issueB(0, 0); writeA(0);                                             \
  __syncthreads();                                                               \
  int buf = 0;                                                                   \
  for (int kt = 0; kt < 8; ++kt) {                                               \
    if (kt + 1 < 8) { loadA(kt + 1); issueB(kt + 1, buf ^ 1); }                  \
    _Pragma("unroll") for (int kk = 0; kk < 2; ++kk) {                           \
      bf16x8 af[4], bfv[4];                                                      \
      _Pragma("unroll") for (int mt = 0; mt < 4; ++mt)                           \
        af[mt] = *(const bf16x8*)&Alds[buf][wr * 64 + mt * 16 + lm][kk * 32 + lg * 8]; \
      _Pragma("unroll") for (int nt = 0; nt < 4; ++nt) {                         \
        int rr = wc * 64 + nt * 16 + lm;                                         \
        int c = (kk * 32 + lg * 8) ^ ((rr & 7) << 3);                            \
        bfv[nt] = *(const bf16x8*)&Blds[buf][rr * 64 + c];                       \
      }                                                                          \
      _Pragma("unroll") for (int mt = 0; mt < 4; ++mt)                           \
      _Pragma("unroll") for (int nt = 0; nt < 4; ++nt)                           \
          acc[mt][nt] = MFMA16(af[mt], bfv[nt], acc[mt][nt]);                    \
    }                                                                            \
    if (kt + 1 < 8) writeA(buf ^ 1);                                             \
    __syncthreads();                                                             \
    buf ^= 1;                                                                    \
  }                                                                              \
  _Pragma("unroll") for (int mt = 0; mt < 4; ++mt)                               \
  _Pragma("unroll") for (int nt = 0; nt < 4; ++nt) {                             \
    int gn = bn * 128 + wc * 64 + nt * 16 + lm;                                  \
    float bv_ = bias[gn];                                                        \
    _Pragma("unroll") for (int e = 0; e < 4; ++e) {                              \
      int gm = bm * 128 + wr * 64 + mt * 16 + lg * 4 + e;                        \
      float v = acc[mt][nt][e] + bv_;                                            \
      size_t off = (size_t)gm * 512 + gn;                                        \
      EPILOGUE                                                                   \
    }                                                                            \
  }

// fused 3 projection GEMMs: blockIdx.y = {0:Q->qb, 1:K->kb, 2:K->vtmp}
__global__ __launch_bounds__(256, 2) void gemm_proj3(
    const float* __restrict__ Q, const float* __restrict__ K,
    const unsigned short* __restrict__ WT,
    const float* __restrict__ bq, const float* __restrict__ bk,
    const float* __restrict__ bv, const float* __restrict__ mask,
    unsigned short* __restrict__ qb, unsigned short* __restrict__ kb,
    unsigned short* __restrict__ vtmp) {
  const int mat = blockIdx.y;
  const float* A = (mat == 0) ? Q : K;
  const unsigned short* W = WT + (size_t)mat * 262144;
  const float* bias = (mat == 0) ? bq : (mat == 1) ? bk : bv;
  unsigned short* outp = (mat == 0) ? qb : (mat == 1) ? kb : vtmp;
  GEMM_BODY(A, W, bias, { outp[off] = f2bf(v * mask[gm]); })
}

// final GEMM: out_f32 = resid + relu(acc + bias) * mask
__global__ __launch_bounds__(256, 2) void gemm_final(
    const float* __restrict__ A, const unsigned short* __restrict__ W,
    const float* __restrict__ bias, const float* __restrict__ mask,
    const float* __restrict__ resid, float* __restrict__ outp) {
  GEMM_BODY(A, W, bias, { outp[off] = resid[off] + fmaxf(v, 0.f) * mask[gm]; })
}

// ---------------------------------------------------------------------------
// v transpose: vtmp[b][n][d] (bf16) -> vT[b][d][n] (bf16)
// ---------------------------------------------------------------------------
__global__ void vtrans_kernel(const unsigned short* __restrict__ vtmp,
                              unsigned short* __restrict__ vT) {
  __shared__ unsigned short T[64][72];
  int b = blockIdx.x, ntile = blockIdx.y, dtile = blockIdx.z;
  int n0 = ntile * 64, d0 = dtile * 64;
  int t = threadIdx.x;
#pragma unroll
  for (int p = 0; p < 2; ++p) {
    int r = (t >> 3) + p * 32;
    int c = (t & 7) * 8;
    *(us8*)&T[r][c] = *(const us8*)&vtmp[((size_t)(b * N_ + n0 + r)) * D_ + d0 + c];
  }
  __syncthreads();
#pragma unroll
  for (int p = 0; p < 2; ++p) {
    int r = (t >> 3) + p * 32;   // d-local
    int c = (t & 7) * 8;         // n-local
    us8 v;
#pragma unroll
    for (int e = 0; e < 8; ++e) v[e] = T[c + e][r];
    *(us8*)&vT[((size_t)(b * D_ + d0 + r)) * N_ + n0 + c] = v;
  }
}

// ---------------------------------------------------------------------------
// attn_fused: block = (h = bid&7, i-tile of 16), 8 waves = 8 batches.
// j-loop: 8 iterations of j-tile 128 (64 KB U/iter, double-buffered = 128 KB
// LDS). ONE barrier per iter; stage(t+1) issued at iter top -> the barrier's
// vmcnt drain IS the HBM pace (roofline), not wasted latency.
//  - U via global_load_lds with involution-swizzled per-lane SOURCE addrs
//    (linear LDS dest): per-b scalar reads spread over 8 banks.
//  - swapped QK^T (mfma(K,Q)): lane owns 32 j's of one i-row -> in-lane
//    softmax, scalar running denominator.
//  - P -> A-frag via 32 __shfl + cndmask (no P in LDS).
// ---------------------------------------------------------------------------
__global__ __launch_bounds__(512, 2) void attn_fused(
    const unsigned short* __restrict__ qb, const unsigned short* __restrict__ kb,
    const unsigned short* __restrict__ vT, const float* __restrict__ U,
    const unsigned* __restrict__ mbits, const float* __restrict__ mask,
    float* __restrict__ O32) {
  __shared__ float Ulds[2][16384];   // 128 KB
  const int t = threadIdx.x, w = t >> 6, l = t & 63;
  const int bid = (int)blockIdx.x;
  const int h = bid & 7;             // XCD-aligned
  const int i0 = (bid >> 3) * 16;
  const int lm = l & 15, lg = l >> 4;

  const float* Ubase = U + (((size_t)h * N_ + i0) * N_) * B_;   // row stride 8192 floats
  const unsigned short* Kb = kb + (size_t)w * N_ * D_ + h * DH_ + lg * 8;
  const unsigned short* Vb = vT + ((size_t)w * D_ + h * DH_ + lm) * N_ + lg * 8;

  // q fragments (B-operand of swapped QK; same lane layout as A-frag)
  bf16x8 qf[2];
#pragma unroll
  for (int kt = 0; kt < 2; ++kt)
    qf[kt] = *(const bf16x8*)&qb[((size_t)w * N_ + i0 + lm) * D_ + h * DH_ + kt * 32 + lg * 8];

  // U LDS addressing constants (granule id G = 256*i + 2*(j-j0) + (b>>2))
  const int xorv = ((lm & 3) << 1) ^ (lg & 1);
  const int Gb = 256 * lm + 8 * lg + (w >> 2);
  const int wc4 = w & 3;

  auto stage = [&](int jt, int sb) {
    const float* Ut = Ubase + (size_t)jt * 1024;   // + j0*8
#pragma unroll
    for (int r = 0; r < 8; ++r) {
      int g = w * 512 + r * 64 + l;
      int G = g ^ (((g >> 8) & 3) << 1) ^ ((g >> 3) & 1);   // involution
      int i = G >> 8, fo = (G & 255) * 4;
      gl_lds16(Ut + (size_t)i * 8192 + fo, &Ulds[sb][g * 4]);
    }
  };

  f32x4 acc[4];
#pragma unroll
  for (int nd = 0; nd < 4; ++nd) acc[nd] = f32x4{0.f, 0.f, 0.f, 0.f};
  float lsum = 0.f;

  const int srcA = lm + ((lg & 1) << 5);
  const int srcB = srcA + 16;
  const bool hi = (lg >> 1) != 0;

  stage(0, 0);
  __syncthreads();

  for (int jt = 0; jt < 8; ++jt) {
    const int cur = jt & 1;
    const int j0 = jt * 128;
    if (jt < 7) stage(jt + 1, cur ^ 1);
    SCHED_PIN();

    // K fragments (A-operand rows j = j0 + js*16 + lm)
    bf16x8 kf[8][2];
#pragma unroll
    for (int js = 0; js < 8; ++js)
#pragma unroll
      for (int kt = 0; kt < 2; ++kt)
        kf[js][kt] = *(const bf16x8*)&Kb[(size_t)(j0 + js * 16 + lm) * D_ + kt * 32];

    // S^T = K @ Q^T : lane (lm,lg) gets S[i=lm][j = j0 + 16*js + 4*lg + e]
    f32x4 S[8];
#pragma unroll
    for (int js = 0; js < 8; ++js) S[js] = f32x4{0.f, 0.f, 0.f, 0.f};
#pragma unroll
    for (int kt = 0; kt < 2; ++kt)
#pragma unroll
      for (int js = 0; js < 8; ++js)
        S[js] = MFMA16(kf[js][kt], qf[kt], S[js]);

    // V fragments for PV
    bf16x8 vf[4][4];
#pragma unroll
    for (int ks = 0; ks < 4; ++ks)
#pragma unroll
      for (int nd = 0; nd < 4; ++nd)
        vf[ks][nd] = *(const bf16x8*)&Vb[(size_t)(nd * 16) * N_ + j0 + ks * 32];

    // softmax numerators, in-lane; pack to bf16
    unsigned pk[8][2];
#pragma unroll
    for (int nt = 0; nt < 8; ++nt) {
      uint4 mb = *(const uint4*)&mbits[j0 + nt * 16 + lg * 4];
      unsigned mbarr[4] = {mb.x, mb.y, mb.z, mb.w};
      float p[4];
#pragma unroll
      for (int e = 0; e < 4; ++e) {
        int gg = (Gb + nt * 32 + e * 2) ^ xorv;
        float u = Ulds[cur][gg * 4 + wc4];
        float s = S[nt][e] * SCALE_ + u;
        p[e] = ((mbarr[e] >> w) & 1) ? exp2f(s * LOG2E_) : 0.f;
        lsum += p[e];
      }
      pk[nt][0] = cvt_pk_bf16(p[0], p[1]);
      pk[nt][1] = cvt_pk_bf16(p[2], p[3]);
    }

    // exchange P to A-frag layout + PV
#pragma unroll
    for (int ks = 0; ks < 4; ++ks) {
      unsigned a0 = __shfl(pk[2 * ks][0], srcA), a1 = __shfl(pk[2 * ks][1], srcA);
      unsigned c0 = __shfl(pk[2 * ks + 1][0], srcA), c1 = __shfl(pk[2 * ks + 1][1], srcA);
      unsigned b0 = __shfl(pk[2 * ks][0], srcB), b1 = __shfl(pk[2 * ks][1], srcB);
      unsigned d0 = __shfl(pk[2 * ks + 1][0], srcB), d1 = __shfl(pk[2 * ks + 1][1], srcB);
      u32x4 fr;
      fr[0] = hi ? c0 : a0;
      fr[1] = hi ? c1 : a1;
      fr[2] = hi ? d0 : b0;
      fr[3] = hi ? d1 : b1;
      bf16x8 paf = __builtin_bit_cast(bf16x8, fr);
#pragma unroll
      for (int nd = 0; nd < 4; ++nd)
        acc[nd] = MFMA16(paf, vf[ks][nd], acc[nd]);
    }

    __syncthreads();   // protects dbuf swap; vmcnt drain = HBM pace
  }

  // row denominators: lanes (lm,*) -> rs(lm)
  lsum += __shfl_xor(lsum, 16);
  lsum += __shfl_xor(lsum, 32);

  // epilogue: O = mask_i * (q + acc / rs);  acc row i = 4*lg+e, col d = nd*16+lm
#pragma unroll
  for (int e = 0; e < 4; ++e) {
    int irow = lg * 4 + e;
    float rs = __shfl(lsum, irow);
    int gi = i0 + irow;
    float mi = mask[w * N_ + gi];
    float rD = 1.f / (rs + 1e-16f);
#pragma unroll
    for (int nd = 0; nd < 4; ++nd) {
      size_t off = ((size_t)w * N_ + gi) * D_ + h * DH_ + nd * 16 + lm;
      O32[off] = mi * (bf2f(qb[off]) + acc[nd][e] * rD);
    }
  }
}

// ---------------------------------------------------------------------------
extern "C" void kernel_launch(void* const* d_in, const int* in_sizes, int n_in,
                              void* d_out, int out_size, void* d_ws, size_t ws_size,
                              hipStream_t stream) {
  const float* Q    = (const float*)d_in[0];
  const float* K    = (const float*)d_in[1];
  const float* U    = (const float*)d_in[2];
  const float* mask = (const float*)d_in[3];
  const float* Wq   = (const float*)d_in[4];
  const float* bq   = (const float*)d_in[5];
  const float* Wk   = (const float*)d_in[6];
  const float* bk   = (const float*)d_in[7];
  const float* Wv   = (const float*)d_in[8];
  const float* bv   = (const float*)d_in[9];
  const float* Wo   = (const float*)d_in[10];
  const float* bo   = (const float*)d_in[11];
  float* out = (float*)d_out;

  char* ws = (char*)d_ws;
  const size_t MB = 1ull << 20;
  unsigned short* WT   = (unsigned short*)(ws);            // [0, 2) MB
  unsigned short* qbuf = (unsigned short*)(ws + 2 * MB);   // [2, 10)
  unsigned short* kbuf = (unsigned short*)(ws + 10 * MB);  // [10, 18)
  unsigned short* vtmp = (unsigned short*)(ws + 18 * MB);  // [18, 26)
  unsigned short* vTb  = (unsigned short*)(ws + 26 * MB);  // [26, 34)
  float*          O32  = (float*)(ws + 34 * MB);           // [34, 50)
  unsigned*       mbits= (unsigned*)(ws + 50 * MB);        // [50, +4KB)

  prep_w<<<4096, 256, 0, stream>>>(Wq, Wk, Wv, Wo, WT);
  prep_mask<<<4, 256, 0, stream>>>(mask, mbits);
  gemm_proj3<<<dim3(256, 3), 256, 0, stream>>>(Q, K, WT, bq, bk, bv, mask, qbuf, kbuf, vtmp);
  vtrans_kernel<<<dim3(8, 16, 8), 256, 0, stream>>>(vtmp, vTb);
  attn_fused<<<512, 512, 0, stream>>>(qbuf, kbuf, vTb, U, mbits, mask, O32);
  gemm_final<<<256, 256, 0, stream>>>(O32, WT + 3 * 262144, bo, mask, O32, out);
}